// Round 9
// baseline (521.729 us; speedup 1.0000x reference)
//
#include <hip/hip_runtime.h>
#include <stdint.h>

typedef __attribute__((ext_vector_type(8))) short short8;
typedef __attribute__((ext_vector_type(4))) float floatx4;

#define DEVI static __device__ __forceinline__

DEVI float b2f(unsigned short u) {
  union { float f; uint32_t i; } v; v.i = ((uint32_t)u) << 16; return v.f;
}
DEVI unsigned short f2b(float f) {
  union { float f; uint32_t i; } v; v.f = f;
  return (unsigned short)((v.i + 0x7fffu + ((v.i >> 16) & 1u)) >> 16);
}
DEVI float readv(const void* p, size_t i, int isf) {
  return isf ? ((const float*)p)[i] : b2f(((const unsigned short*)p)[i]);
}
DEVI unsigned short readb(const void* p, size_t i, int isf) {
  return isf ? f2b(((const float*)p)[i]) : ((const unsigned short*)p)[i];
}

// ---------------------------------------------------------------------------
// B=4 C=64 T=128 F=128 H=128 K=8 L=121 N=512 M=L*N=61952
// xnT[f][n][c]; layer-0 K-order kappa=k*64+c
// U dense: U[row][d*512 + g*128 + h]  (g: 0=z 1=f 2=r 3=hp)
// GEMM k-loops are software-pipelined: prefetch tile k+1 into registers
// between barrier-2 and the MFMA block so global latency overlaps compute.
// ---------------------------------------------------------------------------

__global__ __launch_bounds__(256) void detect_k(const uint32_t* __restrict__ xw,
                                                int* __restrict__ flag) {
  __shared__ int cnt[256];
  int c = 0;
  for (int i = threadIdx.x; i < 2048; i += 256) {
    uint32_t e = (xw[i] >> 23) & 0xFFu;
    c += (e >= 100u && e <= 150u) ? 1 : 0;
  }
  cnt[threadIdx.x] = c;
  __syncthreads();
  for (int s = 128; s > 0; s >>= 1) {
    if (threadIdx.x < s) cnt[threadIdx.x] += cnt[threadIdx.x + s];
    __syncthreads();
  }
  if (threadIdx.x == 0) *flag = (cnt[0] > 1024) ? 1 : 0;
}

// ---- prep: weight transposes + bias conversion ----------------------------
__global__ __launch_bounds__(256) void prep_k(
    const void* W0, const void* W1, const void* W2, const void* W3,
    const void* convW,
    const void* bf0, const void* br0, const void* bf1, const void* br1,
    const void* bf2, const void* br2, const void* bf3, const void* br3,
    const void* convb, const void* gamma, const void* beta,
    const int* __restrict__ flag,
    unsigned short* __restrict__ Wt0, unsigned short* __restrict__ Wt1,
    unsigned short* __restrict__ Wt2, unsigned short* __restrict__ Wt3,
    unsigned short* __restrict__ Bct, unsigned short* __restrict__ biasB,
    unsigned short* __restrict__ convbB, unsigned short* __restrict__ gammaB,
    unsigned short* __restrict__ betaB) {
  const int isf = *flag;
  int idx = blockIdx.x * 256 + threadIdx.x;
  if (idx < 524288) {  // Wt0[d*512+no][kappa]: kappa=64k+c -> kin=c*8+k
    int kap = idx & 511, no = (idx >> 9) & 511, d = idx >> 18;
    int k = kap >> 6, c = kap & 63;
    int kin = c * 8 + k;
    Wt0[idx] = readb(W0, ((size_t)kin * 2 + d) * 512 + no, isf);
  } else if (idx < 1310720) {  // Wt1..3[d*512+no][kin]
    int j = idx - 524288;
    int li = j >> 18;
    int r = j & 262143;
    int kin = r & 255, no = (r >> 8) & 511, d = r >> 17;
    const void* W = (li == 0) ? W1 : (li == 1) ? W2 : W3;
    unsigned short* Wt = (li == 0) ? Wt1 : (li == 1) ? Wt2 : Wt3;
    Wt[r] = readb(W, ((size_t)kin * 2 + d) * 512 + no, isf);
  } else if (idx < 1441792) {  // Bct[cO][kc*256+j]
    int r = idx - 1310720;
    int j = r & 255, k = (r >> 8) & 7, cO = r >> 11;
    Bct[r] = readb(convW, ((size_t)j * 64 + cO) * 8 + k, isf);
  } else if (idx < 1443840) {  // biases
    int r = idx - 1441792;
    int l = r >> 9, rem = r & 511;
    int d = (rem >> 8) & 1, wh = (rem >> 7) & 1, h = rem & 127;
    const void* bfs[4] = {bf0, bf1, bf2, bf3};
    const void* brs[4] = {br0, br1, br2, br3};
    const void* src = wh ? brs[l] : bfs[l];
    biasB[r] = readb(src, d * 128 + h, isf);
  } else if (idx < 1443904) {
    convbB[idx - 1443840] = readb(convb, idx - 1443840, isf);
  } else if (idx < 1443968) {
    gammaB[idx - 1443904] = readb(gamma, idx - 1443904, isf);
  } else if (idx < 1444032) {
    betaB[idx - 1443968] = readb(beta, idx - 1443968, isf);
  }
}

// ---- channel norm -> xnT[f][n][c] -----------------------------------------
__global__ __launch_bounds__(256) void chan_norm(
    const void* __restrict__ x, const int* __restrict__ flag,
    const unsigned short* __restrict__ gammaB, const unsigned short* __restrict__ betaB,
    unsigned short* __restrict__ xnT) {
  const int isf = *flag;
  int tid = blockIdx.x * 256 + threadIdx.x;  // 65536 = B*T*F
  int f = tid & 127, t = (tid >> 7) & 127, b = tid >> 14;
  size_t base = ((size_t)b * 64 * 16384) + (size_t)t * 128 + f;
  float s = 0.f, ss = 0.f;
#pragma unroll 8
  for (int c = 0; c < 64; ++c) {
    float v = readv(x, base + (size_t)c * 16384, isf);
    s += v; ss += v * v;
  }
  float mu = s * (1.f / 64.f);
  float var = ss * (1.f / 64.f) - mu * mu;
  float rs = rsqrtf(var + 1e-8f);
  unsigned short* dst = xnT + ((size_t)f * 512 + (b * 128 + t)) * 64;
#pragma unroll
  for (int c8 = 0; c8 < 8; ++c8) {
    short8 buf;
#pragma unroll
    for (int e = 0; e < 8; ++e) {
      int c = c8 * 8 + e;
      float v = readv(x, base + (size_t)c * 16384, isf);
      buf[e] = (short)f2b(b2f(gammaB[c]) * (v - mu) * rs + b2f(betaB[c]));
    }
    *(short8*)(dst + c8 * 8) = buf;
  }
}

// XCD-affine decode: all NY col-tiles of one row-tile on same XCD, adjacent
DEVI int decode_xy(int bid, int nyShift, int* y) {
  int xs = bid & 7;
  int rest = bid >> 3;
  *y = rest & ((1 << nyShift) - 1);
  return ((rest >> nyShift) << 3) + xs;  // x
}

// ---- layer-0 GEMM from xnT (implicit unfold, pipelined) -------------------
__global__ __launch_bounds__(256) void gemm_l0(
    const unsigned short* __restrict__ xnT, const unsigned short* __restrict__ Bt,
    unsigned short* __restrict__ U, const int Ustr, const int nyShift) {
  __shared__ __align__(16) unsigned short As[128 * 64];
  __shared__ __align__(16) unsigned short Bs[128 * 64];
  int y;
  const int x = decode_xy(blockIdx.x, nyShift, &y);
  if (x >= 484) return;
  const int tid = threadIdx.x;
  const int wave = tid >> 6, lane = tid & 63;
  const int wm = wave >> 1, wn = wave & 1;
  const int q = lane >> 4, l16 = lane & 15;
  const size_t mBase = (size_t)x * 128;
  const int nBase = y * 128;
  const int lBlk = x >> 2;
  const int nBlk = (x & 3) * 128;
  const int sr = tid >> 3, sc = tid & 7;

  floatx4 acc[4][4] = {};
  short8 ra[4], rbv[4];
#pragma unroll
  for (int i = 0; i < 4; ++i) {  // prologue: tile 0
    int r = i * 32 + sr;
    ra[i]  = *(const short8*)(xnT + ((size_t)lBlk * 512 + nBlk + r) * 64 + sc * 8);
    rbv[i] = *(const short8*)(Bt + (size_t)(nBase + r) * 512 + sc * 8);
  }
  for (int kt = 0; kt < 8; ++kt) {  // Kd = 512
    __syncthreads();
#pragma unroll
    for (int i = 0; i < 4; ++i) {
      int r = i * 32 + sr;
      int sl = (sc ^ (r & 7)) << 3;
      *(short8*)&As[r * 64 + sl] = ra[i];
      *(short8*)&Bs[r * 64 + sl] = rbv[i];
    }
    __syncthreads();
    const int ktn = (kt < 7) ? kt + 1 : 7;  // clamped prefetch (harmless refetch)
#pragma unroll
    for (int i = 0; i < 4; ++i) {
      int r = i * 32 + sr;
      ra[i]  = *(const short8*)(xnT + ((size_t)(lBlk + ktn) * 512 + nBlk + r) * 64 + sc * 8);
      rbv[i] = *(const short8*)(Bt + (size_t)(nBase + r) * 512 + (ktn << 6) + sc * 8);
    }
#pragma unroll
    for (int ks = 0; ks < 2; ++ks) {
      const int slot = ks * 4 + q;
      short8 a[4], b[4];
#pragma unroll
      for (int mi = 0; mi < 4; ++mi) {
        int m = wm * 64 + mi * 16 + l16;
        a[mi] = *(const short8*)&As[m * 64 + ((slot ^ (m & 7)) << 3)];
      }
#pragma unroll
      for (int ni = 0; ni < 4; ++ni) {
        int n = wn * 64 + ni * 16 + l16;
        b[ni] = *(const short8*)&Bs[n * 64 + ((slot ^ (n & 7)) << 3)];
      }
#pragma unroll
      for (int mi = 0; mi < 4; ++mi)
#pragma unroll
        for (int ni = 0; ni < 4; ++ni)
          acc[mi][ni] = __builtin_amdgcn_mfma_f32_16x16x32_bf16(a[mi], b[ni], acc[mi][ni], 0, 0, 0);
    }
  }
#pragma unroll
  for (int mi = 0; mi < 4; ++mi) {
#pragma unroll
    for (int ni = 0; ni < 4; ++ni) {
      int col = nBase + wn * 64 + ni * 16 + l16;
#pragma unroll
      for (int r4 = 0; r4 < 4; ++r4) {
        size_t row = mBase + wm * 64 + mi * 16 + q * 4 + r4;
        U[row * Ustr + col] = f2b(acc[mi][ni][r4]);
      }
    }
  }
}

// ---- SRU GEMM layers 1..3 (Kd=256, pipelined) -----------------------------
__global__ __launch_bounds__(256) void gemm_bt(
    const unsigned short* __restrict__ A, const unsigned short* __restrict__ Bt,
    unsigned short* __restrict__ U, const int Ustr, const int nyShift) {
  __shared__ __align__(16) unsigned short As[128 * 64];
  __shared__ __align__(16) unsigned short Bs[128 * 64];
  int y;
  const int x = decode_xy(blockIdx.x, nyShift, &y);
  if (x >= 484) return;
  const int tid = threadIdx.x;
  const int wave = tid >> 6, lane = tid & 63;
  const int wm = wave >> 1, wn = wave & 1;
  const int q = lane >> 4, l16 = lane & 15;
  const size_t mBase = (size_t)x * 128;
  const int nBase = y * 128;
  const int sr = tid >> 3, sc = tid & 7;

  floatx4 acc[4][4] = {};
  short8 ra[4], rbv[4];
#pragma unroll
  for (int i = 0; i < 4; ++i) {  // prologue: tile 0
    int r = i * 32 + sr;
    ra[i]  = *(const short8*)(A  + (mBase + r) * 256 + sc * 8);
    rbv[i] = *(const short8*)(Bt + (size_t)(nBase + r) * 256 + sc * 8);
  }
  for (int kt = 0; kt < 4; ++kt) {  // Kd = 256
    __syncthreads();
#pragma unroll
    for (int i = 0; i < 4; ++i) {
      int r = i * 32 + sr;
      int sl = (sc ^ (r & 7)) << 3;
      *(short8*)&As[r * 64 + sl] = ra[i];
      *(short8*)&Bs[r * 64 + sl] = rbv[i];
    }
    __syncthreads();
    const int ktn = (kt < 3) ? kt + 1 : 3;
#pragma unroll
    for (int i = 0; i < 4; ++i) {
      int r = i * 32 + sr;
      ra[i]  = *(const short8*)(A  + (mBase + r) * 256 + (ktn << 6) + sc * 8);
      rbv[i] = *(const short8*)(Bt + (size_t)(nBase + r) * 256 + (ktn << 6) + sc * 8);
    }
#pragma unroll
    for (int ks = 0; ks < 2; ++ks) {
      const int slot = ks * 4 + q;
      short8 a[4], b[4];
#pragma unroll
      for (int mi = 0; mi < 4; ++mi) {
        int m = wm * 64 + mi * 16 + l16;
        a[mi] = *(const short8*)&As[m * 64 + ((slot ^ (m & 7)) << 3)];
      }
#pragma unroll
      for (int ni = 0; ni < 4; ++ni) {
        int n = wn * 64 + ni * 16 + l16;
        b[ni] = *(const short8*)&Bs[n * 64 + ((slot ^ (n & 7)) << 3)];
      }
#pragma unroll
      for (int mi = 0; mi < 4; ++mi)
#pragma unroll
        for (int ni = 0; ni < 4; ++ni)
          acc[mi][ni] = __builtin_amdgcn_mfma_f32_16x16x32_bf16(a[mi], b[ni], acc[mi][ni], 0, 0, 0);
    }
  }
#pragma unroll
  for (int mi = 0; mi < 4; ++mi) {
#pragma unroll
    for (int ni = 0; ni < 4; ++ni) {
      int col = nBase + wn * 64 + ni * 16 + l16;
#pragma unroll
      for (int r4 = 0; r4 < 4; ++r4) {
        size_t row = mBase + wm * 64 + mi * 16 + q * 4 + r4;
        U[row * Ustr + col] = f2b(acc[mi][ni][r4]);
      }
    }
  }
}

// ---- SRU recurrence + highway: 8-deep ring, compile-time ring indices -----
__global__ __launch_bounds__(256) void sru_scan(
    const unsigned short* __restrict__ U, const int Ustr,
    const unsigned short* __restrict__ bias, unsigned short* __restrict__ hout,
    const int dual, const int dir0) {
  const int gid = blockIdx.x * 256 + threadIdx.x;
  const int dir = dual ? (gid >> 16) : dir0;
  const int t = gid & 65535;
  const int n = t >> 7, h = t & 127;
  const float bfc = b2f(bias[dir * 256 + h]);
  const float brc = b2f(bias[dir * 256 + 128 + h]);
  const long long stepU = dir ? -(512LL * Ustr) : (512LL * Ustr);
  const long long stepO = dir ? -(512LL * 256LL) : (512LL * 256LL);
  const int l0 = dir ? 120 : 0;
  const int colBase = (Ustr == 1024) ? dir * 512 : 0;
  const unsigned short* pz = U + (size_t)(l0 * 512 + n) * Ustr + colBase + h;
  unsigned short* pO = hout + ((size_t)(l0 * 512 + n)) * 256 + dir * 128 + h;

  ushort4 ring[8];  // .x=z .y=f .z=r .w=hp ; slot j holds step (base+j)
#pragma unroll
  for (int i = 0; i < 8; ++i) {
    const unsigned short* p = pz + i * stepU;
    ring[i].x = p[0]; ring[i].y = p[128]; ring[i].z = p[256]; ring[i].w = p[384];
  }
  float c = 0.f;
  for (int base = 0; base < 120; base += 8) {  // steps 0..119 (15 groups)
#pragma unroll
    for (int j = 0; j < 8; ++j) {
      ushort4 v = ring[j];
      int s = base + j;
      int pre = s + 8; if (pre > 120) pre = 120;  // clamp (harmless refetch)
      const unsigned short* p = pz + (long long)(pre - s) * stepU;
      ring[j].x = p[0]; ring[j].y = p[128]; ring[j].z = p[256]; ring[j].w = p[384];
      float z = b2f(v.x), fr = b2f(v.y), rr = b2f(v.z), hp = b2f(v.w);
      float fg = 1.f / (1.f + __expf(-(fr + bfc)));
      float rg = 1.f / (1.f + __expf(-(rr + brc)));
      c = fg * c + (1.f - fg) * z;
      *pO = f2b(rg * c + (1.f - rg) * hp);
      pz += stepU; pO += stepO;
    }
  }
  {  // final step 120 (in ring[0])
    ushort4 v = ring[0];
    float z = b2f(v.x), fr = b2f(v.y), rr = b2f(v.z), hp = b2f(v.w);
    float fg = 1.f / (1.f + __expf(-(fr + bfc)));
    float rg = 1.f / (1.f + __expf(-(rr + brc)));
    c = fg * c + (1.f - fg) * z;
    *pO = f2b(rg * c + (1.f - rg) * hp);
  }
}

// ---- conv-transpose: block per n; M=cO(64), N=f(128), K=2048, pipelined ---
__global__ __launch_bounds__(256) void gemm_conv(
    const unsigned short* __restrict__ h3, const unsigned short* __restrict__ Bct,
    const unsigned short* __restrict__ convbB, const unsigned short* __restrict__ xnT,
    const int* __restrict__ flag, void* __restrict__ out) {
  __shared__ __align__(16) unsigned short As[64 * 64];   // cO x K
  __shared__ __align__(16) unsigned short Bs[128 * 64];  // f x K
  const int n = blockIdx.x;
  const int bb = n >> 7, t = n & 127;
  const int tid = threadIdx.x;
  const int wave = tid >> 6, lane = tid & 63;
  const int q = lane >> 4, l16 = lane & 15;
  const int sr = tid >> 3, sc = tid & 7;
  const int isf = *flag;

  floatx4 acc[4][2] = {};
  short8 ra[2], rbv[4];
  {  // prologue: kt = 0
#pragma unroll
    for (int i = 0; i < 2; ++i)
      ra[i] = *(const short8*)(Bct + (size_t)(i * 32 + sr) * 2048 + sc * 8);
#pragma unroll
    for (int i = 0; i < 4; ++i) {
      int f = i * 32 + sr;
      short8 v = {};
      if (f >= 0 && f < 121)  // kc=0: l=f
        v = *(const short8*)(h3 + ((size_t)(f * 512 + n)) * 256 + sc * 8);
      rbv[i] = v;
    }
  }
  for (int kt = 0; kt < 32; ++kt) {  // K = 2048
    __syncthreads();
#pragma unroll
    for (int i = 0; i < 2; ++i) {
      int r = i * 32 + sr;
      *(short8*)&As[r * 64 + ((sc ^ (r & 7)) << 3)] = ra[i];
    }
#pragma unroll
    for (int i = 0; i < 4; ++i) {
      int f = i * 32 + sr;
      *(short8*)&Bs[f * 64 + ((sc ^ (f & 7)) << 3)] = rbv[i];
    }
    __syncthreads();
    const int ktn = (kt < 31) ? kt + 1 : 31;
    {
      const int k0n = ktn << 6;
      const int kcn = ktn >> 2;
      const int j0n = (ktn & 3) * 64 + sc * 8;
#pragma unroll
      for (int i = 0; i < 2; ++i)
        ra[i] = *(const short8*)(Bct + (size_t)(i * 32 + sr) * 2048 + k0n + sc * 8);
#pragma unroll
      for (int i = 0; i < 4; ++i) {
        int f = i * 32 + sr;
        int l = f - kcn;
        short8 v = {};
        if (l >= 0 && l < 121)
          v = *(const short8*)(h3 + ((size_t)(l * 512 + n)) * 256 + j0n);
        rbv[i] = v;
      }
    }
#pragma unroll
    for (int ks = 0; ks < 2; ++ks) {
      const int slot = ks * 4 + q;
      short8 a[4], b[2];
#pragma unroll
      for (int mi = 0; mi < 4; ++mi) {
        int m = mi * 16 + l16;  // cO
        a[mi] = *(const short8*)&As[m * 64 + ((slot ^ (m & 7)) << 3)];
      }
#pragma unroll
      for (int ni = 0; ni < 2; ++ni) {
        int f = wave * 32 + ni * 16 + l16;
        b[ni] = *(const short8*)&Bs[f * 64 + ((slot ^ (f & 7)) << 3)];
      }
#pragma unroll
      for (int mi = 0; mi < 4; ++mi)
#pragma unroll
        for (int ni = 0; ni < 2; ++ni)
          acc[mi][ni] = __builtin_amdgcn_mfma_f32_16x16x32_bf16(a[mi], b[ni], acc[mi][ni], 0, 0, 0);
    }
  }
#pragma unroll
  for (int mi = 0; mi < 4; ++mi) {
#pragma unroll
    for (int ni = 0; ni < 2; ++ni) {
      int f = wave * 32 + ni * 16 + l16;
#pragma unroll
      for (int r4 = 0; r4 < 4; ++r4) {
        int cO = mi * 16 + q * 4 + r4;
        float cb = b2f(convbB[cO]);
        float resid = b2f(xnT[((size_t)f * 512 + n) * 64 + cO]);
        size_t oi = (((size_t)bb * 64 + cO) * 128 + t) * 128 + f;
        float val = acc[mi][ni][r4] + cb + resid;
        if (isf) ((float*)out)[oi] = val;
        else ((unsigned short*)out)[oi] = f2b(val);
      }
    }
  }
}

// ---------------------------------------------------------------------------
extern "C" void kernel_launch(void* const* d_in, const int* in_sizes, int n_in,
                              void* d_out, int out_size, void* d_ws, size_t ws_size,
                              hipStream_t stream) {
  const void* x     = d_in[0];
  const void* gamma = d_in[1];
  const void* beta  = d_in[2];
  const void* W[4]  = {d_in[3], d_in[6], d_in[9], d_in[12]};
  const void* bfp[4] = {d_in[4], d_in[7], d_in[10], d_in[13]};
  const void* brp[4] = {d_in[5], d_in[8], d_in[11], d_in[14]};
  const void* convW = d_in[15];
  const void* convb = d_in[16];

  unsigned short* wsb = (unsigned short*)d_ws;
  int* flag             = (int*)wsb;          // 16 el
  unsigned short* biasB  = wsb + 16;          // 2048
  unsigned short* convbB = wsb + 2064;        // 64
  unsigned short* gammaB = wsb + 2128;        // 64
  unsigned short* betaB  = wsb + 2192;        // 64 (pad -> 2304)
  unsigned short* Wt0 = wsb + 2304;           // 524,288
  unsigned short* Wt1 = Wt0 + 524288;         // 262,144
  unsigned short* Wt2 = Wt1 + 262144;
  unsigned short* Wt3 = Wt2 + 262144;
  unsigned short* Bct = Wt3 + 262144;         // 131,072
  unsigned short* xnT = Bct + 131072;         // 4,194,304
  unsigned short* hA  = xnT + 4194304;        // 15,859,712
  unsigned short* hB  = hA + 15859712;        // 15,859,712
  unsigned short* U   = hB + 15859712;        // 31.7M (nonfused) / 63.4M (fused)

  const int fused = (ws_size >= (size_t)100796672 * 2) ? 1 : 0;

  detect_k<<<1, 256, 0, stream>>>((const uint32_t*)x, flag);
  prep_k<<<5641, 256, 0, stream>>>(W[0], W[1], W[2], W[3], convW,
                                   bfp[0], brp[0], bfp[1], brp[1],
                                   bfp[2], brp[2], bfp[3], brp[3],
                                   convb, gamma, beta, flag,
                                   Wt0, Wt1, Wt2, Wt3, Bct, biasB, convbB, gammaB, betaB);
  chan_norm<<<256, 256, 0, stream>>>(x, flag, gammaB, betaB, xnT);

  const unsigned short* hin[4] = {nullptr, hA, hB, hA};
  unsigned short* hout_[4]     = {hA, hB, hA, hB};
  const unsigned short* Wt_[4] = {Wt0, Wt1, Wt2, Wt3};
  const int Kd_[4] = {512, 256, 256, 256};

  for (int li = 0; li < 4; ++li) {
    if (fused) {
      const int grid = 8 * 8 * 61;
      if (li == 0) gemm_l0<<<grid, 256, 0, stream>>>(xnT, Wt0, U, 1024, 3);
      else         gemm_bt<<<grid, 256, 0, stream>>>(hin[li], Wt_[li], U, 1024, 3);
      sru_scan<<<512, 256, 0, stream>>>(U, 1024, biasB + li * 512, hout_[li], 1, 0);
    } else {
      const int grid = 8 * 4 * 61;
      for (int d = 0; d < 2; ++d) {
        if (li == 0) gemm_l0<<<grid, 256, 0, stream>>>(xnT, Wt0 + (size_t)d * 512 * 512, U, 512, 2);
        else         gemm_bt<<<grid, 256, 0, stream>>>(hin[li], Wt_[li] + (size_t)d * 512 * Kd_[li], U, 512, 2);
        sru_scan<<<256, 256, 0, stream>>>(U, 512, biasB + li * 512, hout_[li], 0, d);
      }
    }
  }
  gemm_conv<<<512, 256, 0, stream>>>(hB, Bct, convbB, xnT, flag, d_out);
}

// Round 10
// 483.044 us; speedup vs baseline: 1.0801x; 1.0801x over previous
//
#include <hip/hip_runtime.h>
#include <stdint.h>

typedef __attribute__((ext_vector_type(8))) short short8;
typedef __attribute__((ext_vector_type(4))) float floatx4;

#define DEVI static __device__ __forceinline__

DEVI float b2f(unsigned short u) {
  union { float f; uint32_t i; } v; v.i = ((uint32_t)u) << 16; return v.f;
}
DEVI unsigned short f2b(float f) {
  union { float f; uint32_t i; } v; v.f = f;
  return (unsigned short)((v.i + 0x7fffu + ((v.i >> 16) & 1u)) >> 16);
}
DEVI float readv(const void* p, size_t i, int isf) {
  return isf ? ((const float*)p)[i] : b2f(((const unsigned short*)p)[i]);
}
DEVI unsigned short readb(const void* p, size_t i, int isf) {
  return isf ? f2b(((const float*)p)[i]) : ((const unsigned short*)p)[i];
}

// ---------------------------------------------------------------------------
// B=4 C=64 T=128 F=128 H=128 K=8 L=121 N=512 M=L*N=61952
// xnT[f][n][c]; layer-0 K-order kappa=k*64+c
// U dense: U[row][d*512 + g*128 + h]  (g: 0=z 1=f 2=r 3=hp)
// gemm_l0: software-pipelined (verified -4us). gemm_bt/conv: plain (r8).
// ---------------------------------------------------------------------------

__global__ __launch_bounds__(256) void detect_k(const uint32_t* __restrict__ xw,
                                                int* __restrict__ flag) {
  __shared__ int cnt[256];
  int c = 0;
  for (int i = threadIdx.x; i < 2048; i += 256) {
    uint32_t e = (xw[i] >> 23) & 0xFFu;
    c += (e >= 100u && e <= 150u) ? 1 : 0;
  }
  cnt[threadIdx.x] = c;
  __syncthreads();
  for (int s = 128; s > 0; s >>= 1) {
    if (threadIdx.x < s) cnt[threadIdx.x] += cnt[threadIdx.x + s];
    __syncthreads();
  }
  if (threadIdx.x == 0) *flag = (cnt[0] > 1024) ? 1 : 0;
}

// ---- prep: weight transposes + bias conversion ----------------------------
__global__ __launch_bounds__(256) void prep_k(
    const void* W0, const void* W1, const void* W2, const void* W3,
    const void* convW,
    const void* bf0, const void* br0, const void* bf1, const void* br1,
    const void* bf2, const void* br2, const void* bf3, const void* br3,
    const void* convb, const void* gamma, const void* beta,
    const int* __restrict__ flag,
    unsigned short* __restrict__ Wt0, unsigned short* __restrict__ Wt1,
    unsigned short* __restrict__ Wt2, unsigned short* __restrict__ Wt3,
    unsigned short* __restrict__ Bct, unsigned short* __restrict__ biasB,
    unsigned short* __restrict__ convbB, unsigned short* __restrict__ gammaB,
    unsigned short* __restrict__ betaB) {
  const int isf = *flag;
  int idx = blockIdx.x * 256 + threadIdx.x;
  if (idx < 524288) {  // Wt0[d*512+no][kappa]: kappa=64k+c -> kin=c*8+k
    int kap = idx & 511, no = (idx >> 9) & 511, d = idx >> 18;
    int k = kap >> 6, c = kap & 63;
    int kin = c * 8 + k;
    Wt0[idx] = readb(W0, ((size_t)kin * 2 + d) * 512 + no, isf);
  } else if (idx < 1310720) {  // Wt1..3[d*512+no][kin]
    int j = idx - 524288;
    int li = j >> 18;
    int r = j & 262143;
    int kin = r & 255, no = (r >> 8) & 511, d = r >> 17;
    const void* W = (li == 0) ? W1 : (li == 1) ? W2 : W3;
    unsigned short* Wt = (li == 0) ? Wt1 : (li == 1) ? Wt2 : Wt3;
    Wt[r] = readb(W, ((size_t)kin * 2 + d) * 512 + no, isf);
  } else if (idx < 1441792) {  // Bct[cO][kc*256+j]
    int r = idx - 1310720;
    int j = r & 255, k = (r >> 8) & 7, cO = r >> 11;
    Bct[r] = readb(convW, ((size_t)j * 64 + cO) * 8 + k, isf);
  } else if (idx < 1443840) {  // biases
    int r = idx - 1441792;
    int l = r >> 9, rem = r & 511;
    int d = (rem >> 8) & 1, wh = (rem >> 7) & 1, h = rem & 127;
    const void* bfs[4] = {bf0, bf1, bf2, bf3};
    const void* brs[4] = {br0, br1, br2, br3};
    const void* src = wh ? brs[l] : bfs[l];
    biasB[r] = readb(src, d * 128 + h, isf);
  } else if (idx < 1443904) {
    convbB[idx - 1443840] = readb(convb, idx - 1443840, isf);
  } else if (idx < 1443968) {
    gammaB[idx - 1443904] = readb(gamma, idx - 1443904, isf);
  } else if (idx < 1444032) {
    betaB[idx - 1443968] = readb(beta, idx - 1443968, isf);
  }
}

// ---- channel norm -> xnT[f][n][c] -----------------------------------------
__global__ __launch_bounds__(256) void chan_norm(
    const void* __restrict__ x, const int* __restrict__ flag,
    const unsigned short* __restrict__ gammaB, const unsigned short* __restrict__ betaB,
    unsigned short* __restrict__ xnT) {
  const int isf = *flag;
  int tid = blockIdx.x * 256 + threadIdx.x;  // 65536 = B*T*F
  int f = tid & 127, t = (tid >> 7) & 127, b = tid >> 14;
  size_t base = ((size_t)b * 64 * 16384) + (size_t)t * 128 + f;
  float s = 0.f, ss = 0.f;
#pragma unroll 8
  for (int c = 0; c < 64; ++c) {
    float v = readv(x, base + (size_t)c * 16384, isf);
    s += v; ss += v * v;
  }
  float mu = s * (1.f / 64.f);
  float var = ss * (1.f / 64.f) - mu * mu;
  float rs = rsqrtf(var + 1e-8f);
  unsigned short* dst = xnT + ((size_t)f * 512 + (b * 128 + t)) * 64;
#pragma unroll
  for (int c8 = 0; c8 < 8; ++c8) {
    short8 buf;
#pragma unroll
    for (int e = 0; e < 8; ++e) {
      int c = c8 * 8 + e;
      float v = readv(x, base + (size_t)c * 16384, isf);
      buf[e] = (short)f2b(b2f(gammaB[c]) * (v - mu) * rs + b2f(betaB[c]));
    }
    *(short8*)(dst + c8 * 8) = buf;
  }
}

// XCD-affine decode: all NY col-tiles of one row-tile on same XCD, adjacent
DEVI int decode_xy(int bid, int nyShift, int* y) {
  int xs = bid & 7;
  int rest = bid >> 3;
  *y = rest & ((1 << nyShift) - 1);
  return ((rest >> nyShift) << 3) + xs;  // x
}

// ---- layer-0 GEMM from xnT (implicit unfold, pipelined) -------------------
__global__ __launch_bounds__(256) void gemm_l0(
    const unsigned short* __restrict__ xnT, const unsigned short* __restrict__ Bt,
    unsigned short* __restrict__ U, const int Ustr, const int nyShift) {
  __shared__ __align__(16) unsigned short As[128 * 64];
  __shared__ __align__(16) unsigned short Bs[128 * 64];
  int y;
  const int x = decode_xy(blockIdx.x, nyShift, &y);
  if (x >= 484) return;
  const int tid = threadIdx.x;
  const int wave = tid >> 6, lane = tid & 63;
  const int wm = wave >> 1, wn = wave & 1;
  const int q = lane >> 4, l16 = lane & 15;
  const size_t mBase = (size_t)x * 128;
  const int nBase = y * 128;
  const int lBlk = x >> 2;
  const int nBlk = (x & 3) * 128;
  const int sr = tid >> 3, sc = tid & 7;

  floatx4 acc[4][4] = {};
  short8 ra[4], rbv[4];
#pragma unroll
  for (int i = 0; i < 4; ++i) {  // prologue: tile 0
    int r = i * 32 + sr;
    ra[i]  = *(const short8*)(xnT + ((size_t)lBlk * 512 + nBlk + r) * 64 + sc * 8);
    rbv[i] = *(const short8*)(Bt + (size_t)(nBase + r) * 512 + sc * 8);
  }
  for (int kt = 0; kt < 8; ++kt) {  // Kd = 512
    __syncthreads();
#pragma unroll
    for (int i = 0; i < 4; ++i) {
      int r = i * 32 + sr;
      int sl = (sc ^ (r & 7)) << 3;
      *(short8*)&As[r * 64 + sl] = ra[i];
      *(short8*)&Bs[r * 64 + sl] = rbv[i];
    }
    __syncthreads();
    const int ktn = (kt < 7) ? kt + 1 : 7;  // clamped prefetch
#pragma unroll
    for (int i = 0; i < 4; ++i) {
      int r = i * 32 + sr;
      ra[i]  = *(const short8*)(xnT + ((size_t)(lBlk + ktn) * 512 + nBlk + r) * 64 + sc * 8);
      rbv[i] = *(const short8*)(Bt + (size_t)(nBase + r) * 512 + (ktn << 6) + sc * 8);
    }
#pragma unroll
    for (int ks = 0; ks < 2; ++ks) {
      const int slot = ks * 4 + q;
      short8 a[4], b[4];
#pragma unroll
      for (int mi = 0; mi < 4; ++mi) {
        int m = wm * 64 + mi * 16 + l16;
        a[mi] = *(const short8*)&As[m * 64 + ((slot ^ (m & 7)) << 3)];
      }
#pragma unroll
      for (int ni = 0; ni < 4; ++ni) {
        int n = wn * 64 + ni * 16 + l16;
        b[ni] = *(const short8*)&Bs[n * 64 + ((slot ^ (n & 7)) << 3)];
      }
#pragma unroll
      for (int mi = 0; mi < 4; ++mi)
#pragma unroll
        for (int ni = 0; ni < 4; ++ni)
          acc[mi][ni] = __builtin_amdgcn_mfma_f32_16x16x32_bf16(a[mi], b[ni], acc[mi][ni], 0, 0, 0);
    }
  }
#pragma unroll
  for (int mi = 0; mi < 4; ++mi) {
#pragma unroll
    for (int ni = 0; ni < 4; ++ni) {
      int col = nBase + wn * 64 + ni * 16 + l16;
#pragma unroll
      for (int r4 = 0; r4 < 4; ++r4) {
        size_t row = mBase + wm * 64 + mi * 16 + q * 4 + r4;
        U[row * Ustr + col] = f2b(acc[mi][ni][r4]);
      }
    }
  }
}

// ---- SRU GEMM layers 1..3 (Kd=256, non-pipelined r8 version) --------------
__global__ __launch_bounds__(256) void gemm_bt(
    const unsigned short* __restrict__ A, const unsigned short* __restrict__ Bt,
    unsigned short* __restrict__ U, const int Ustr, const int nyShift) {
  __shared__ __align__(16) unsigned short As[128 * 64];
  __shared__ __align__(16) unsigned short Bs[128 * 64];
  int y;
  const int x = decode_xy(blockIdx.x, nyShift, &y);
  if (x >= 484) return;
  const int tid = threadIdx.x;
  const int wave = tid >> 6, lane = tid & 63;
  const int wm = wave >> 1, wn = wave & 1;
  const int q = lane >> 4, l16 = lane & 15;
  const size_t mBase = (size_t)x * 128;
  const int nBase = y * 128;
  const int sr = tid >> 3, sc = tid & 7;

  floatx4 acc[4][4] = {};
  for (int kt = 0; kt < 4; ++kt) {  // Kd = 256
    const int k0 = kt << 6;
    short8 ra[4], rbv[4];
#pragma unroll
    for (int i = 0; i < 4; ++i) {
      int r = i * 32 + sr;
      ra[i]  = *(const short8*)(A  + (mBase + r) * 256 + k0 + sc * 8);
      rbv[i] = *(const short8*)(Bt + (size_t)(nBase + r) * 256 + k0 + sc * 8);
    }
    __syncthreads();
#pragma unroll
    for (int i = 0; i < 4; ++i) {
      int r = i * 32 + sr;
      int sl = (sc ^ (r & 7)) << 3;
      *(short8*)&As[r * 64 + sl] = ra[i];
      *(short8*)&Bs[r * 64 + sl] = rbv[i];
    }
    __syncthreads();
#pragma unroll
    for (int ks = 0; ks < 2; ++ks) {
      const int slot = ks * 4 + q;
      short8 a[4], b[4];
#pragma unroll
      for (int mi = 0; mi < 4; ++mi) {
        int m = wm * 64 + mi * 16 + l16;
        a[mi] = *(const short8*)&As[m * 64 + ((slot ^ (m & 7)) << 3)];
      }
#pragma unroll
      for (int ni = 0; ni < 4; ++ni) {
        int n = wn * 64 + ni * 16 + l16;
        b[ni] = *(const short8*)&Bs[n * 64 + ((slot ^ (n & 7)) << 3)];
      }
#pragma unroll
      for (int mi = 0; mi < 4; ++mi)
#pragma unroll
        for (int ni = 0; ni < 4; ++ni)
          acc[mi][ni] = __builtin_amdgcn_mfma_f32_16x16x32_bf16(a[mi], b[ni], acc[mi][ni], 0, 0, 0);
    }
  }
#pragma unroll
  for (int mi = 0; mi < 4; ++mi) {
#pragma unroll
    for (int ni = 0; ni < 4; ++ni) {
      int col = nBase + wn * 64 + ni * 16 + l16;
#pragma unroll
      for (int r4 = 0; r4 < 4; ++r4) {
        size_t row = mBase + wm * 64 + mi * 16 + q * 4 + r4;
        U[row * Ustr + col] = f2b(acc[mi][ni][r4]);
      }
    }
  }
}

// ---- SRU recurrence + highway: 8-deep ring, compile-time ring indices -----
__global__ __launch_bounds__(256) void sru_scan(
    const unsigned short* __restrict__ U, const int Ustr,
    const unsigned short* __restrict__ bias, unsigned short* __restrict__ hout,
    const int dual, const int dir0) {
  const int gid = blockIdx.x * 256 + threadIdx.x;
  const int dir = dual ? (gid >> 16) : dir0;
  const int t = gid & 65535;
  const int n = t >> 7, h = t & 127;
  const float bfc = b2f(bias[dir * 256 + h]);
  const float brc = b2f(bias[dir * 256 + 128 + h]);
  const long long stepU = dir ? -(512LL * Ustr) : (512LL * Ustr);
  const long long stepO = dir ? -(512LL * 256LL) : (512LL * 256LL);
  const int l0 = dir ? 120 : 0;
  const int colBase = (Ustr == 1024) ? dir * 512 : 0;
  const unsigned short* pz = U + (size_t)(l0 * 512 + n) * Ustr + colBase + h;
  unsigned short* pO = hout + ((size_t)(l0 * 512 + n)) * 256 + dir * 128 + h;

  ushort4 ring[8];
#pragma unroll
  for (int i = 0; i < 8; ++i) {
    const unsigned short* p = pz + i * stepU;
    ring[i].x = p[0]; ring[i].y = p[128]; ring[i].z = p[256]; ring[i].w = p[384];
  }
  float c = 0.f;
  for (int base = 0; base < 120; base += 8) {  // steps 0..119 (15 groups)
#pragma unroll
    for (int j = 0; j < 8; ++j) {
      ushort4 v = ring[j];
      int s = base + j;
      int pre = s + 8; if (pre > 120) pre = 120;  // clamp
      const unsigned short* p = pz + (long long)(pre - s) * stepU;
      ring[j].x = p[0]; ring[j].y = p[128]; ring[j].z = p[256]; ring[j].w = p[384];
      float z = b2f(v.x), fr = b2f(v.y), rr = b2f(v.z), hp = b2f(v.w);
      float fg = 1.f / (1.f + __expf(-(fr + bfc)));
      float rg = 1.f / (1.f + __expf(-(rr + brc)));
      c = fg * c + (1.f - fg) * z;
      *pO = f2b(rg * c + (1.f - rg) * hp);
      pz += stepU; pO += stepO;
    }
  }
  {  // final step 120
    ushort4 v = ring[0];
    float z = b2f(v.x), fr = b2f(v.y), rr = b2f(v.z), hp = b2f(v.w);
    float fg = 1.f / (1.f + __expf(-(fr + bfc)));
    float rg = 1.f / (1.f + __expf(-(rr + brc)));
    c = fg * c + (1.f - fg) * z;
    *pO = f2b(rg * c + (1.f - rg) * hp);
  }
}

// ---- conv-transpose: block per n (non-pipelined r8 version) ---------------
__global__ __launch_bounds__(256) void gemm_conv(
    const unsigned short* __restrict__ h3, const unsigned short* __restrict__ Bct,
    const unsigned short* __restrict__ convbB, const unsigned short* __restrict__ xnT,
    const int* __restrict__ flag, void* __restrict__ out) {
  __shared__ __align__(16) unsigned short As[64 * 64];   // cO x K
  __shared__ __align__(16) unsigned short Bs[128 * 64];  // f x K
  const int n = blockIdx.x;
  const int bb = n >> 7, t = n & 127;
  const int tid = threadIdx.x;
  const int wave = tid >> 6, lane = tid & 63;
  const int q = lane >> 4, l16 = lane & 15;
  const int sr = tid >> 3, sc = tid & 7;
  const int isf = *flag;

  floatx4 acc[4][2] = {};
  for (int kt = 0; kt < 32; ++kt) {  // K = 2048
    const int k0 = kt << 6;
    const int kc = kt >> 2;          // conv tap 0..7
    const int j0 = (kt & 3) * 64 + sc * 8;
    short8 ra[2], rbv[4];
#pragma unroll
    for (int i = 0; i < 2; ++i) {
      int r = i * 32 + sr;  // cO 0..63
      ra[i] = *(const short8*)(Bct + (size_t)r * 2048 + k0 + sc * 8);
    }
#pragma unroll
    for (int i = 0; i < 4; ++i) {
      int f = i * 32 + sr;  // 0..127
      int l = f - kc;
      short8 v = {};
      if (l >= 0 && l < 121)
        v = *(const short8*)(h3 + ((size_t)(l * 512 + n)) * 256 + j0);
      rbv[i] = v;
    }
    __syncthreads();
#pragma unroll
    for (int i = 0; i < 2; ++i) {
      int r = i * 32 + sr;
      *(short8*)&As[r * 64 + ((sc ^ (r & 7)) << 3)] = ra[i];
    }
#pragma unroll
    for (int i = 0; i < 4; ++i) {
      int f = i * 32 + sr;
      *(short8*)&Bs[f * 64 + ((sc ^ (f & 7)) << 3)] = rbv[i];
    }
    __syncthreads();
#pragma unroll
    for (int ks = 0; ks < 2; ++ks) {
      const int slot = ks * 4 + q;
      short8 a[4], b[2];
#pragma unroll
      for (int mi = 0; mi < 4; ++mi) {
        int m = mi * 16 + l16;  // cO
        a[mi] = *(const short8*)&As[m * 64 + ((slot ^ (m & 7)) << 3)];
      }
#pragma unroll
      for (int ni = 0; ni < 2; ++ni) {
        int f = wave * 32 + ni * 16 + l16;
        b[ni] = *(const short8*)&Bs[f * 64 + ((slot ^ (f & 7)) << 3)];
      }
#pragma unroll
      for (int mi = 0; mi < 4; ++mi)
#pragma unroll
        for (int ni = 0; ni < 2; ++ni)
          acc[mi][ni] = __builtin_amdgcn_mfma_f32_16x16x32_bf16(a[mi], b[ni], acc[mi][ni], 0, 0, 0);
    }
  }
#pragma unroll
  for (int mi = 0; mi < 4; ++mi) {
#pragma unroll
    for (int ni = 0; ni < 2; ++ni) {
      int f = wave * 32 + ni * 16 + l16;
#pragma unroll
      for (int r4 = 0; r4 < 4; ++r4) {
        int cO = mi * 16 + q * 4 + r4;
        float cb = b2f(convbB[cO]);
        float resid = b2f(xnT[((size_t)f * 512 + n) * 64 + cO]);
        size_t oi = (((size_t)bb * 64 + cO) * 128 + t) * 128 + f;
        float val = acc[mi][ni][r4] + cb + resid;
        if (isf) ((float*)out)[oi] = val;
        else ((unsigned short*)out)[oi] = f2b(val);
      }
    }
  }
}

// ---------------------------------------------------------------------------
extern "C" void kernel_launch(void* const* d_in, const int* in_sizes, int n_in,
                              void* d_out, int out_size, void* d_ws, size_t ws_size,
                              hipStream_t stream) {
  const void* x     = d_in[0];
  const void* gamma = d_in[1];
  const void* beta  = d_in[2];
  const void* W[4]  = {d_in[3], d_in[6], d_in[9], d_in[12]};
  const void* bfp[4] = {d_in[4], d_in[7], d_in[10], d_in[13]};
  const void* brp[4] = {d_in[5], d_in[8], d_in[11], d_in[14]};
  const void* convW = d_in[15];
  const void* convb = d_in[16];

  unsigned short* wsb = (unsigned short*)d_ws;
  int* flag             = (int*)wsb;          // 16 el
  unsigned short* biasB  = wsb + 16;          // 2048
  unsigned short* convbB = wsb + 2064;        // 64
  unsigned short* gammaB = wsb + 2128;        // 64
  unsigned short* betaB  = wsb + 2192;        // 64 (pad -> 2304)
  unsigned short* Wt0 = wsb + 2304;           // 524,288
  unsigned short* Wt1 = Wt0 + 524288;         // 262,144
  unsigned short* Wt2 = Wt1 + 262144;
  unsigned short* Wt3 = Wt2 + 262144;
  unsigned short* Bct = Wt3 + 262144;         // 131,072
  unsigned short* xnT = Bct + 131072;         // 4,194,304
  unsigned short* hA  = xnT + 4194304;        // 15,859,712
  unsigned short* hB  = hA + 15859712;        // 15,859,712
  unsigned short* U   = hB + 15859712;        // 31.7M (nonfused) / 63.4M (fused)

  const int fused = (ws_size >= (size_t)100796672 * 2) ? 1 : 0;

  detect_k<<<1, 256, 0, stream>>>((const uint32_t*)x, flag);
  prep_k<<<5641, 256, 0, stream>>>(W[0], W[1], W[2], W[3], convW,
                                   bfp[0], brp[0], bfp[1], brp[1],
                                   bfp[2], brp[2], bfp[3], brp[3],
                                   convb, gamma, beta, flag,
                                   Wt0, Wt1, Wt2, Wt3, Bct, biasB, convbB, gammaB, betaB);
  chan_norm<<<256, 256, 0, stream>>>(x, flag, gammaB, betaB, xnT);

  const unsigned short* hin[4] = {nullptr, hA, hB, hA};
  unsigned short* hout_[4]     = {hA, hB, hA, hB};
  const unsigned short* Wt_[4] = {Wt0, Wt1, Wt2, Wt3};
  const int Kd_[4] = {512, 256, 256, 256};

  for (int li = 0; li < 4; ++li) {
    if (fused) {
      const int grid = 8 * 8 * 61;
      if (li == 0) gemm_l0<<<grid, 256, 0, stream>>>(xnT, Wt0, U, 1024, 3);
      else         gemm_bt<<<grid, 256, 0, stream>>>(hin[li], Wt_[li], U, 1024, 3);
      sru_scan<<<512, 256, 0, stream>>>(U, 1024, biasB + li * 512, hout_[li], 1, 0);
    } else {
      const int grid = 8 * 4 * 61;
      for (int d = 0; d < 2; ++d) {
        if (li == 0) gemm_l0<<<grid, 256, 0, stream>>>(xnT, Wt0 + (size_t)d * 512 * 512, U, 512, 2);
        else         gemm_bt<<<grid, 256, 0, stream>>>(hin[li], Wt_[li] + (size_t)d * 512 * Kd_[li], U, 512, 2);
        sru_scan<<<256, 256, 0, stream>>>(U, 512, biasB + li * 512, hout_[li], 0, d);
      }
    }
  }
  gemm_conv<<<512, 256, 0, stream>>>(hB, Bct, convbB, xnT, flag, d_out);
}